// Round 9
// baseline (218.059 us; speedup 1.0000x reference)
//
#include <hip/hip_runtime.h>

typedef unsigned short u16;
typedef unsigned int u32;
typedef __attribute__((ext_vector_type(8))) short bf16x8;
typedef __attribute__((ext_vector_type(4))) short bf16x4;
typedef __attribute__((ext_vector_type(4))) float f32x4;

#define MFMA(a, b, c) __builtin_amdgcn_mfma_f32_16x16x32_bf16((a), (b), (c), 0, 0, 0)
#define MFMA16(a, b, c) __builtin_amdgcn_mfma_f32_16x16x16bf16_1k((a), (b), (c), 0, 0, 0)

// round-to-nearest-even f32 -> bf16
static __device__ __forceinline__ u16 f2bf(float x) {
  u32 u = __float_as_uint(x);
  u += 0x7FFFu + ((u >> 16) & 1u);
  return (u16)(u >> 16);
}
// pack two f32 -> (bf16(hi)<<16)|bf16(lo), truncating (hot paths)
static __device__ __forceinline__ u32 packbf_t(float hi, float lo) {
  return __builtin_amdgcn_perm(__float_as_uint(hi), __float_as_uint(lo), 0x07060302u);
}
// rounded pack: lo | hi<<16
static __device__ __forceinline__ u32 packbf(float lo, float hi) {
  return (u32)f2bf(lo) | ((u32)f2bf(hi) << 16);
}
// load 8 consecutive fp32 -> bf16x8 (rounded)
static __device__ __forceinline__ bf16x8 ld8bf(const float* __restrict__ p) {
  const float4 a = *(const float4*)p;
  const float4 b = *(const float4*)(p + 4);
  union { u32 u[4]; bf16x8 v; } r;
  r.u[0] = packbf(a.x, a.y);
  r.u[1] = packbf(a.z, a.w);
  r.u[2] = packbf(b.x, b.y);
  r.u[3] = packbf(b.z, b.w);
  return r.v;
}

// ---------------------------------------------------------------------------
// Kernel 1: fused projections + attention, K eliminated algebraically:
//   S = Q·K^T = (Q·Wk)·x^T + Q·bk  ->  precompute QW = Q·Wk (once/block)
//   and cq = Q·bk (folded into MFMA acc init). Per key-chunk the bf16 x
//   fragment feeds S^T directly (A=x, B=QW) -- no K-proj, no LDS in loop.
//   V-proj per chunk: MFMA(A=x, B=Wv) C/D output IS the PV MFMA16 A-frag
//   (register-only, r8-verified). exp(S^T) C/D layout IS the MFMA16 B-frag
//   (r6-verified). Single-pass unnormalized softmax (|s| <~ 10).
// Block = 32 queries x 4 waves (wave w owns keys [w*256, w*256+256) in 16
// chunks of 16); cross-wave combine via bf16 LDS at end (overlays init LDS).
// grid 1024 = 16 b (XCD-affine) x 2 br x 32 qh; 4 blocks/CU target.
// ---------------------------------------------------------------------------
__global__ __launch_bounds__(256, 4) void fused_attn_kernel(
    const float* __restrict__ h, const float* __restrict__ m_,
    const float* __restrict__ Wq, const float* __restrict__ bq,
    const float* __restrict__ Wk, const float* __restrict__ bk,
    const float* __restrict__ Wk2, const float* __restrict__ bk2,
    const float* __restrict__ Wv, const float* __restrict__ bv,
    const float* __restrict__ Wv2, const float* __restrict__ bv2,
    u16* __restrict__ hbuf, u16* __restrict__ Ztb)
{
  const int id = blockIdx.x;
  const int b = id & 15;            // batch -> fixed XCD (id%8 == b%8)
  const int br = (id >> 4) & 1;
  const int qh = id >> 5;           // 0..31
  const float* __restrict__ X = (br ? m_ : h) + b * 65536;  // (64c,1024px)
  const float* __restrict__ H = h + b * 65536;
  const float* __restrict__ WK = br ? Wk2 : Wk;
  const float* __restrict__ BK = br ? bk2 : bk;
  const float* __restrict__ WV = br ? Wv2 : Wv;
  const float* __restrict__ BV = br ? bv2 : bv;

  __shared__ __align__(16) u16 pool[8704];  // 17.4 KB: Qlds+QWlds, later zcb
  __shared__ float rsw[4][32];
  __shared__ float cql[32];
  u16* const Qlds = pool;           // 32 x 72 (init only)
  u16* const QWlds = pool + 2304;   // 32 x 72 (init only)
  u16* const zcb = pool;            // 4 x 32 x 68 (after K-loop)

  const int tid = threadIdx.x, w = tid >> 6, lane = tid & 63;
  const int mm = lane & 15, q = lane >> 4;
  const int q0 = qh * 32;

  // V weights as B-frags: B[n=c_out][k=c_in]
  bf16x8 wvB0[4], wvB1[4];
  float bvs[4];
#pragma unroll
  for (int ot = 0; ot < 4; ++ot) {
    wvB0[ot] = ld8bf(WV + (ot * 16 + mm) * 64 + q * 8);
    wvB1[ot] = ld8bf(WV + (ot * 16 + mm) * 64 + 32 + q * 8);
    bvs[ot] = BV[ot * 16 + mm];
  }

  // ---- init phase 1 (waves 0,1): Q-proj for 32 queries, cq = Q·bk
  if (w < 2) {
    const int qp = q0 + w * 16 + mm;  // this lane's query pixel
    float xq[16];
#pragma unroll
    for (int i = 0; i < 2; ++i)
#pragma unroll
      for (int j = 0; j < 8; ++j)
        xq[i * 8 + j] = H[(i * 32 + q * 8 + j) * 1024 + qp];
    union { u32 u[4]; bf16x8 v; } x0, x1;
#pragma unroll
    for (int p = 0; p < 4; ++p) {
      x0.u[p] = packbf(xq[2 * p], xq[2 * p + 1]);
      x1.u[p] = packbf(xq[8 + 2 * p], xq[9 + 2 * p]);
    }
    if (br == 0) {  // emit bf16 h^T tile
      u16* hp = hbuf + (b * 1024 + qp) * 64;
      uint4 h0, h1;
      h0.x = x0.u[0]; h0.y = x0.u[1]; h0.z = x0.u[2]; h0.w = x0.u[3];
      h1.x = x1.u[0]; h1.y = x1.u[1]; h1.z = x1.u[2]; h1.w = x1.u[3];
      *(uint4*)(hp + q * 8) = h0;
      *(uint4*)(hp + 32 + q * 8) = h1;
    }
    float cqp = 0.f;
#pragma unroll
    for (int ot = 0; ot < 4; ++ot) {
      const bf16x8 wa0 = ld8bf(Wq + (ot * 16 + mm) * 64 + q * 8);
      const bf16x8 wa1 = ld8bf(Wq + (ot * 16 + mm) * 64 + 32 + q * 8);
      const float4 b4 = *(const float4*)(bq + ot * 16 + q * 4);
      f32x4 d = {b4.x, b4.y, b4.z, b4.w};
      d = MFMA(wa0, x0.v, d);   // D[d-row][query=mm]
      d = MFMA(wa1, x1.v, d);
      const float4 bkv = *(const float4*)(BK + ot * 16 + q * 4);
      cqp += d[0] * bkv.x + d[1] * bkv.y + d[2] * bkv.z + d[3] * bkv.w;
      uint2 val;
      val.x = packbf(d[0], d[1]);
      val.y = packbf(d[2], d[3]);
      *(uint2*)(Qlds + (w * 16 + mm) * 72 + ot * 16 + q * 4) = val;
    }
    cqp += __shfl_xor(cqp, 16);
    cqp += __shfl_xor(cqp, 32);
    if (q == 0) cql[w * 16 + mm] = cqp;
  }
  __syncthreads();

  // ---- init phase 2 (waves 0,1): QW = Q·Wk  (D[c-row][query])
  if (w < 2) {
    const bf16x8 qB0 = *(const bf16x8*)(Qlds + (w * 16 + mm) * 72 + q * 8);
    const bf16x8 qB1 = *(const bf16x8*)(Qlds + (w * 16 + mm) * 72 + 32 + q * 8);
#pragma unroll
    for (int ct2 = 0; ct2 < 4; ++ct2) {
      union { u32 u[4]; bf16x8 v; } a0, a1;
#pragma unroll
      for (int jp = 0; jp < 4; ++jp) {
        const float w00 = WK[(q * 8 + 2 * jp) * 64 + ct2 * 16 + mm];
        const float w01 = WK[(q * 8 + 2 * jp + 1) * 64 + ct2 * 16 + mm];
        const float w10 = WK[(32 + q * 8 + 2 * jp) * 64 + ct2 * 16 + mm];
        const float w11 = WK[(32 + q * 8 + 2 * jp + 1) * 64 + ct2 * 16 + mm];
        a0.u[jp] = packbf(w00, w01);
        a1.u[jp] = packbf(w10, w11);
      }
      f32x4 d = {0.f, 0.f, 0.f, 0.f};
      d = MFMA(a0.v, qB0, d);
      d = MFMA(a1.v, qB1, d);
      uint2 val;
      val.x = packbf(d[0], d[1]);
      val.y = packbf(d[2], d[3]);
      *(uint2*)(QWlds + (w * 16 + mm) * 72 + ct2 * 16 + q * 4) = val;
    }
  }
  __syncthreads();

  // QW B-frags + cq for this wave's 2 query tiles
  bf16x8 qwf0[2], qwf1[2];
  float cq2[2];
#pragma unroll
  for (int qt = 0; qt < 2; ++qt) {
    qwf0[qt] = *(const bf16x8*)(QWlds + (qt * 16 + mm) * 72 + q * 8);
    qwf1[qt] = *(const bf16x8*)(QWlds + (qt * 16 + mm) * 72 + 32 + q * 8);
    cq2[qt] = cql[qt * 16 + mm];
  }

  f32x4 z[2][4];  // [qt][ct]: D[c=ct*16+q*4+r][query=qt*16+mm] partial
#pragma unroll
  for (int qt = 0; qt < 2; ++qt)
#pragma unroll
    for (int ct = 0; ct < 4; ++ct) z[qt][ct] = (f32x4){0.f, 0.f, 0.f, 0.f};
  float rp[2] = {0.f, 0.f};

  // ---- K-loop: wave w owns keys [w*256, w*256+256), 16-key chunks.
  // No LDS, no barriers: x frag -> {V-proj, S^T} -> exp -> PV, all register.
#pragma unroll 1
  for (int kc = 0; kc < 16; ++kc) {
    const int px = w * 256 + kc * 16 + mm;
    union { u32 u[4]; bf16x8 v; } xb0, xb1;
#pragma unroll
    for (int jp = 0; jp < 4; ++jp) {
      const float f00 = X[(q * 8 + 2 * jp) * 1024 + px];
      const float f01 = X[(q * 8 + 2 * jp + 1) * 1024 + px];
      const float f10 = X[(32 + q * 8 + 2 * jp) * 1024 + px];
      const float f11 = X[(32 + q * 8 + 2 * jp + 1) * 1024 + px];
      xb0.u[jp] = packbf(f00, f01);
      xb1.u[jp] = packbf(f10, f11);
    }

    // V-proj: D[key-row][c_out=mm] == PV MFMA16 A-frag (A[m=c][k=key])
    bf16x4 vf[4];
#pragma unroll
    for (int ct = 0; ct < 4; ++ct) {
      f32x4 d = {bvs[ct], bvs[ct], bvs[ct], bvs[ct]};
      d = MFMA(xb0.v, wvB0[ct], d);
      d = MFMA(xb1.v, wvB1[ct], d);
      union { u32 u[2]; bf16x4 v; } pv;
      pv.u[0] = packbf_t(d[1], d[0]);
      pv.u[1] = packbf_t(d[3], d[2]);
      vf[ct] = pv.v;
    }

    // S^T = x·QW^T + cq: D[key-row][query=mm]; exp -> MFMA16 B-frag
#pragma unroll
    for (int qt = 0; qt < 2; ++qt) {
      f32x4 s = {cq2[qt], cq2[qt], cq2[qt], cq2[qt]};
      s = MFMA(xb0.v, qwf0[qt], s);
      s = MFMA(xb1.v, qwf1[qt], s);
      const float e0 = __expf(s[0]), e1 = __expf(s[1]);
      const float e2 = __expf(s[2]), e3 = __expf(s[3]);
      rp[qt] += (e0 + e1) + (e2 + e3);
      union { u32 u[2]; bf16x4 v; } pb;
      pb.u[0] = packbf_t(e1, e0);
      pb.u[1] = packbf_t(e3, e2);
#pragma unroll
      for (int ct = 0; ct < 4; ++ct) z[qt][ct] = MFMA16(vf[ct], pb.v, z[qt][ct]);
    }
  }

  __syncthreads();  // pool overlay: Q/QW frags all consumed by now

  // ---- publish partials
#pragma unroll
  for (int qt = 0; qt < 2; ++qt) {
    float v = rp[qt];
    v += __shfl_xor(v, 16);
    v += __shfl_xor(v, 32);
    if (q == 0) rsw[w][qt * 16 + mm] = v;
#pragma unroll
    for (int ct = 0; ct < 4; ++ct) {
      uint2 val;
      val.x = packbf_t(z[qt][ct][1], z[qt][ct][0]);
      val.y = packbf_t(z[qt][ct][3], z[qt][ct][2]);
      *(uint2*)(zcb + w * 2176 + (qt * 16 + mm) * 68 + ct * 16 + q * 4) = val;
    }
  }
  __syncthreads();

  // ---- combine 4 key-splits, normalize, store bf16 (B,N,128)
  const int c2 = tid & 31, qr = tid >> 5;
#pragma unroll
  for (int i = 0; i < 4; ++i) {
    const int query = qr + i * 8;
    const float rt = rsw[0][query] + rsw[1][query] + rsw[2][query] + rsw[3][query];
    const float rinv = __builtin_amdgcn_rcpf(rt);
    float vlo = 0.f, vhi = 0.f;
#pragma unroll
    for (int ww = 0; ww < 4; ++ww) {
      const u32 u = *(const u32*)(zcb + ww * 2176 + query * 68 + c2 * 2);
      vlo += __uint_as_float(u << 16);
      vhi += __uint_as_float(u & 0xffff0000u);
    }
    vlo *= rinv;
    vhi *= rinv;
    *(u32*)(Ztb + (b * 1024 + q0 + query) * 128 + br * 64 + c2 * 2) = packbf_t(vhi, vlo);
  }
}

// ---------------------------------------------------------------------------
// Kernel 2: fused zproj (128->128) + final (192->192) + gates, all MFMA.
// Weights converted fp32->bf16 inline; gate-major row index computed inline.
// grid (16 b, 32 nt): linear%8 == b%8 matches fused_attn's Ztb writers.
// ---------------------------------------------------------------------------
__global__ __launch_bounds__(256) void tail_kernel(
    const u16* __restrict__ Ztb, const u16* __restrict__ hbuf,
    const float* __restrict__ m_, const float* __restrict__ Wz,
    const float* __restrict__ bz, const float* __restrict__ Wm,
    const float* __restrict__ bm, float* __restrict__ out)
{
  const int b = blockIdx.x, n0 = blockIdx.y * 32;
  __shared__ __align__(16) u16 zp[32][136];  // bf16 Zp tile [px][c]
  const int tid = threadIdx.x, lane = tid & 63, wv = tid >> 6;
  const int mm = lane & 15, q = lane >> 4;
  const int pxt = wv & 1, oh = wv >> 1;

  // ---- Phase A: Zp = Wz @ [Zh;Zm] + bz  (A=W: lane rows = contiguous o-ch)
  {
    bf16x8 za[4];
#pragma unroll
    for (int ks = 0; ks < 4; ++ks)
      za[ks] = *(const bf16x8*)(Ztb + (b * 1024 + n0 + pxt * 16 + mm) * 128 +
                                ks * 32 + q * 8);
#pragma unroll
    for (int ot = 0; ot < 4; ++ot) {
      const int o0 = oh * 64 + ot * 16;
      const float4 b4 = *(const float4*)(bz + o0 + q * 4);
      f32x4 d = {b4.x, b4.y, b4.z, b4.w};
#pragma unroll
      for (int ks = 0; ks < 4; ++ks) {
        const bf16x8 wb = ld8bf(Wz + (o0 + mm) * 128 + ks * 32 + q * 8);
        d = MFMA(wb, za[ks], d);
      }
      uint2 val;
      val.x = packbf(d[0], d[1]);
      val.y = packbf(d[2], d[3]);
      *(uint2*)&zp[pxt * 16 + mm][o0 + q * 4] = val;
    }
  }
  __syncthreads();

  // ---- Phase B: combined = Wm @ [Zp; h] + bm (gate-major row o inline)
  {
    const int hb2 = oh;
    bf16x8 fa[6];
#pragma unroll
    for (int ks = 0; ks < 4; ++ks)
      fa[ks] = *(const bf16x8*)&zp[pxt * 16 + mm][ks * 32 + q * 8];
    {
      const u16* hp = hbuf + (b * 1024 + n0 + pxt * 16 + mm) * 64;
      fa[4] = *(const bf16x8*)(hp + q * 8);
      fa[5] = *(const bf16x8*)(hp + 32 + q * 8);
    }
    f32x4 dd[6];
#pragma unroll
    for (int j = 0; j < 6; ++j) {
      const int o = (j % 3) * 64 + (hb2 * 2 + j / 3) * 16 + mm;
      const float bb = bm[o];
      f32x4 d = {bb, bb, bb, bb};
#pragma unroll
      for (int ks = 0; ks < 6; ++ks) {
        const bf16x8 wb = ld8bf(Wm + o * 192 + ks * 32 + q * 8);
        d = MFMA(fa[ks], wb, d);
      }
      dd[j] = d;
    }
#pragma unroll
    for (int ctl = 0; ctl < 2; ++ctl) {
      const int c = (hb2 * 2 + ctl) * 16 + mm;
      const int px = n0 + pxt * 16 + q * 4;
      const float4 mold = *(const float4*)(m_ + (b * 64 + c) * 1024 + px);
      float4 nh, nm;
#pragma unroll
      for (int r = 0; r < 4; ++r) {
        const float xo = dd[ctl * 3 + 0][r];
        const float xg = dd[ctl * 3 + 1][r];
        const float xi = dd[ctl * 3 + 2][r];
        const float si = __builtin_amdgcn_rcpf(1.f + __expf(-xi));
        const float th = 1.f - 2.f * __builtin_amdgcn_rcpf(__expf(2.f * xg) + 1.f);
        const float so = __builtin_amdgcn_rcpf(1.f + __expf(-xo));
        const float mo = ((const float*)&mold)[r];
        const float nmv = (1.f - si) * mo + si * th;
        ((float*)&nm)[r] = nmv;
        ((float*)&nh)[r] = so * nmv;
      }
      *(float4*)(out + (b * 64 + c) * 1024 + px) = nh;
      *(float4*)(out + 1048576 + (b * 64 + c) * 1024 + px) = nm;
    }
  }
}

// ---------------------------------------------------------------------------
extern "C" void kernel_launch(void* const* d_in, const int* in_sizes, int n_in,
                              void* d_out, int out_size, void* d_ws, size_t ws_size,
                              hipStream_t stream) {
  const float* h   = (const float*)d_in[0];
  const float* m   = (const float*)d_in[1];
  const float* Wq  = (const float*)d_in[2];
  const float* bq  = (const float*)d_in[3];
  const float* Wk  = (const float*)d_in[4];
  const float* bk  = (const float*)d_in[5];
  const float* Wk2 = (const float*)d_in[6];
  const float* bk2 = (const float*)d_in[7];
  const float* Wv  = (const float*)d_in[8];
  const float* bv  = (const float*)d_in[9];
  const float* Wv2 = (const float*)d_in[10];
  const float* bv2 = (const float*)d_in[11];
  const float* Wz  = (const float*)d_in[12];
  const float* bz  = (const float*)d_in[13];
  const float* Wm  = (const float*)d_in[14];
  const float* bm  = (const float*)d_in[15];
  float* out = (float*)d_out;

  char* ws = (char*)d_ws;
  const size_t MB = 1024 * 1024;
  u16* hbuf = (u16*)(ws + 0 * MB);   // (B,N,64) bf16
  u16* Ztb  = (u16*)(ws + 2 * MB);   // (B,N,128) bf16

  fused_attn_kernel<<<1024, 256, 0, stream>>>(h, m, Wq, bq, Wk, bk, Wk2, bk2,
                                              Wv, bv, Wv2, bv2, hbuf, Ztb);
  tail_kernel<<<dim3(16, 32), 256, 0, stream>>>(Ztb, hbuf, m, Wz, bz, Wm, bm, out);
}

// Round 11
// 145.520 us; speedup vs baseline: 1.4985x; 1.4985x over previous
//
#include <hip/hip_runtime.h>

typedef unsigned short u16;
typedef unsigned int u32;
typedef __attribute__((ext_vector_type(8))) short bf16x8;
typedef __attribute__((ext_vector_type(4))) short bf16x4;
typedef __attribute__((ext_vector_type(4))) float f32x4;

#define MFMA(a, b, c) __builtin_amdgcn_mfma_f32_16x16x32_bf16((a), (b), (c), 0, 0, 0)
#define MFMA16(a, b, c) __builtin_amdgcn_mfma_f32_16x16x16bf16_1k((a), (b), (c), 0, 0, 0)

// round-to-nearest-even f32 -> bf16
static __device__ __forceinline__ u16 f2bf(float x) {
  u32 u = __float_as_uint(x);
  u += 0x7FFFu + ((u >> 16) & 1u);
  return (u16)(u >> 16);
}
// pack two f32 -> (bf16(hi)<<16)|bf16(lo), truncating (hot paths)
static __device__ __forceinline__ u32 packbf_t(float hi, float lo) {
  return __builtin_amdgcn_perm(__float_as_uint(hi), __float_as_uint(lo), 0x07060302u);
}
// rounded pack: lo | hi<<16
static __device__ __forceinline__ u32 packbf(float lo, float hi) {
  return (u32)f2bf(lo) | ((u32)f2bf(hi) << 16);
}
// load 8 consecutive fp32 -> bf16x8 (rounded)
static __device__ __forceinline__ bf16x8 ld8bf(const float* __restrict__ p) {
  const float4 a = *(const float4*)p;
  const float4 b = *(const float4*)(p + 4);
  union { u32 u[4]; bf16x8 v; } r;
  r.u[0] = packbf(a.x, a.y);
  r.u[1] = packbf(a.z, a.w);
  r.u[2] = packbf(b.x, b.y);
  r.u[3] = packbf(b.z, b.w);
  return r.v;
}

// ---------------------------------------------------------------------------
// Kernel 0: transpose h,m -> bf16 (B,N,64) via LDS. Coalesced fp32 reads,
// 2x uint4 writes per (px,sg) thread (16 u16 each -- r10's bug was writing
// only 8 of 16). grid (16 b, 16 nt): linear%8 == b%8 -> XCD-local writes.
// ---------------------------------------------------------------------------
__global__ __launch_bounds__(256) void prep_kernel(
    const float* __restrict__ h, const float* __restrict__ m_,
    u16* __restrict__ hbuf, u16* __restrict__ mbuf)
{
  const int b = blockIdx.x, n0 = blockIdx.y * 64;
  __shared__ __align__(16) u16 t[2][64][72];
  const int tid = threadIdx.x;
  {
    const int px = tid & 63, c0 = (tid >> 6) * 16;
#pragma unroll
    for (int i = 0; i < 8; ++i) {
      const int c = c0 + 2 * i;
      const int o0 = (b * 64 + c) * 1024 + n0 + px;
      *(u32*)&t[0][px][c] = packbf(h[o0], h[o0 + 1024]);
      *(u32*)&t[1][px][c] = packbf(m_[o0], m_[o0 + 1024]);
    }
  }
  __syncthreads();
  const int px = tid >> 2, sg = tid & 3;
  const int ofs = (b * 1024 + n0 + px) * 64 + sg * 16;
  *(uint4*)(hbuf + ofs)     = *(const uint4*)&t[0][px][sg * 16];
  *(uint4*)(hbuf + ofs + 8) = *(const uint4*)&t[0][px][sg * 16 + 8];
  *(uint4*)(mbuf + ofs)     = *(const uint4*)&t[1][px][sg * 16];
  *(uint4*)(mbuf + ofs + 8) = *(const uint4*)&t[1][px][sg * 16 + 8];
}

// ---------------------------------------------------------------------------
// Kernel 1: fused projections + attention, K eliminated algebraically:
//   S = Q·K^T = (Q·Wk)·x^T + Q·bk -> QW precomputed once/block, cq folded
//   into the MFMA accumulator init. K-loop is register-only: coalesced
//   bf16x8 x-frag -> {V-proj (C/D == PV MFMA16 A-frag), S^T (exp C/D ==
//   MFMA16 B-frag)} -> PV. Single-pass unnormalized softmax (|s| <~ 10).
// Block = 64 queries x 4 waves (wave w owns keys [w*256,(w+1)*256) in 16
// chunks of 16, manual next-chunk prefetch); bf16 LDS combine at end.
// grid 512 = 16 b (XCD-affine) x 2 br x 16 qh -> 16 blocks per (b,br)
// streaming the same 128 KB bf16 X in the same order (L2 convoy).
// ---------------------------------------------------------------------------
__global__ __launch_bounds__(256, 2) void fused_attn_kernel(
    const u16* __restrict__ hbuf, const u16* __restrict__ mbuf,
    const float* __restrict__ Wq, const float* __restrict__ bq,
    const float* __restrict__ Wk, const float* __restrict__ bk,
    const float* __restrict__ Wk2, const float* __restrict__ bk2,
    const float* __restrict__ Wv, const float* __restrict__ bv,
    const float* __restrict__ Wv2, const float* __restrict__ bv2,
    u16* __restrict__ Ztb)
{
  const int id = blockIdx.x;
  const int b = id & 15;            // batch -> fixed XCD (id%8 == b%8)
  const int br = (id >> 4) & 1;
  const int qh = id >> 5;           // 0..15
  const u16* __restrict__ X = (br ? mbuf : hbuf) + b * 65536;  // (1024px,64c)
  const u16* __restrict__ Hq = hbuf + b * 65536;
  const float* __restrict__ WK = br ? Wk2 : Wk;
  const float* __restrict__ BK = br ? bk2 : bk;
  const float* __restrict__ WV = br ? Wv2 : Wv;
  const float* __restrict__ BV = br ? bv2 : bv;

  __shared__ __align__(16) u16 pool[17408];  // Qlds+QWlds (2x4608), later zcb
  __shared__ float rsw[4][64];
  __shared__ float cql[64];
  u16* const Qlds = pool;           // 64 x 72 (init only)
  u16* const QWlds = pool + 4608;   // 64 x 72 (init only)
  u16* const zcb = pool;            // 4 x 64 x 68 (after K-loop barrier)

  const int tid = threadIdx.x, w = tid >> 6, lane = tid & 63;
  const int mm = lane & 15, q = lane >> 4;
  const int q0 = qh * 64;

  // V weights as B-frags: B[n=c_out][k=c_in]
  bf16x8 wvB0[4], wvB1[4];
  float bvs[4];
#pragma unroll
  for (int ot = 0; ot < 4; ++ot) {
    wvB0[ot] = ld8bf(WV + (ot * 16 + mm) * 64 + q * 8);
    wvB1[ot] = ld8bf(WV + (ot * 16 + mm) * 64 + 32 + q * 8);
    bvs[ot] = BV[ot * 16 + mm];
  }

  // ---- init 1: Q-proj for this wave's 16 queries; cq = Q·bk
  {
    const int qp = q0 + w * 16 + mm;
    const bf16x8 x0 = *(const bf16x8*)(Hq + qp * 64 + q * 8);
    const bf16x8 x1 = *(const bf16x8*)(Hq + qp * 64 + 32 + q * 8);
    float cqp = 0.f;
#pragma unroll
    for (int ot = 0; ot < 4; ++ot) {
      const bf16x8 wa0 = ld8bf(Wq + (ot * 16 + mm) * 64 + q * 8);
      const bf16x8 wa1 = ld8bf(Wq + (ot * 16 + mm) * 64 + 32 + q * 8);
      const float4 b4 = *(const float4*)(bq + ot * 16 + q * 4);
      f32x4 d = {b4.x, b4.y, b4.z, b4.w};
      d = MFMA(wa0, x0, d);   // D[o-row][query=mm]
      d = MFMA(wa1, x1, d);
      const float4 bkv = *(const float4*)(BK + ot * 16 + q * 4);
      cqp += d[0] * bkv.x + d[1] * bkv.y + d[2] * bkv.z + d[3] * bkv.w;
      uint2 val;
      val.x = packbf(d[0], d[1]);
      val.y = packbf(d[2], d[3]);
      *(uint2*)(Qlds + (w * 16 + mm) * 72 + ot * 16 + q * 4) = val;
    }
    cqp += __shfl_xor(cqp, 16);
    cqp += __shfl_xor(cqp, 32);
    if (q == 0) cql[w * 16 + mm] = cqp;
  }
  __syncthreads();

  // ---- init 2: QW = Wk^T·Q for this wave's query tile (D[c_in-row][query])
  {
    const bf16x8 qB0 = *(const bf16x8*)(Qlds + (w * 16 + mm) * 72 + q * 8);
    const bf16x8 qB1 = *(const bf16x8*)(Qlds + (w * 16 + mm) * 72 + 32 + q * 8);
#pragma unroll
    for (int ct2 = 0; ct2 < 4; ++ct2) {
      union { u32 u[4]; bf16x8 v; } a0, a1;
#pragma unroll
      for (int jp = 0; jp < 4; ++jp) {
        const float w00 = WK[(q * 8 + 2 * jp) * 64 + ct2 * 16 + mm];
        const float w01 = WK[(q * 8 + 2 * jp + 1) * 64 + ct2 * 16 + mm];
        const float w10 = WK[(32 + q * 8 + 2 * jp) * 64 + ct2 * 16 + mm];
        const float w11 = WK[(32 + q * 8 + 2 * jp + 1) * 64 + ct2 * 16 + mm];
        a0.u[jp] = packbf(w00, w01);
        a1.u[jp] = packbf(w10, w11);
      }
      f32x4 d = {0.f, 0.f, 0.f, 0.f};
      d = MFMA(a0.v, qB0, d);
      d = MFMA(a1.v, qB1, d);
      uint2 val;
      val.x = packbf(d[0], d[1]);
      val.y = packbf(d[2], d[3]);
      *(uint2*)(QWlds + (w * 16 + mm) * 72 + ct2 * 16 + q * 4) = val;
    }
  }
  __syncthreads();

  // QW B-frags + cq for all 4 query tiles
  bf16x8 qwf0[4], qwf1[4];
  float cq4[4];
#pragma unroll
  for (int qt = 0; qt < 4; ++qt) {
    qwf0[qt] = *(const bf16x8*)(QWlds + (qt * 16 + mm) * 72 + q * 8);
    qwf1[qt] = *(const bf16x8*)(QWlds + (qt * 16 + mm) * 72 + 32 + q * 8);
    cq4[qt] = cql[qt * 16 + mm];
  }

  f32x4 z[4][4];  // [qt][ct]: D[c=ct*16+q*4+r][query=qt*16+mm] partial
#pragma unroll
  for (int qt = 0; qt < 4; ++qt)
#pragma unroll
    for (int ct = 0; ct < 4; ++ct) z[qt][ct] = (f32x4){0.f, 0.f, 0.f, 0.f};
  float rp[4] = {0.f, 0.f, 0.f, 0.f};

  // ---- K-loop: wave w owns keys [w*256,(w+1)*256), 16-key chunks,
  // coalesced bf16x8 loads + manual next-chunk prefetch. No LDS, no barriers.
  bf16x8 xc0, xc1, xn0, xn1;
  {
    const u16* p = X + (w * 256 + mm) * 64;
    xc0 = *(const bf16x8*)(p + q * 8);
    xc1 = *(const bf16x8*)(p + 32 + q * 8);
  }
#pragma unroll 1
  for (int kc = 0; kc < 16; ++kc) {
    if (kc < 15) {
      const u16* p = X + (w * 256 + (kc + 1) * 16 + mm) * 64;
      xn0 = *(const bf16x8*)(p + q * 8);
      xn1 = *(const bf16x8*)(p + 32 + q * 8);
    }

    // V-proj: D[key-row][c_out=mm] == PV MFMA16 A-frag (A[m=c][k=key])
    bf16x4 vf[4];
#pragma unroll
    for (int ct = 0; ct < 4; ++ct) {
      f32x4 d = {bvs[ct], bvs[ct], bvs[ct], bvs[ct]};
      d = MFMA(xc0, wvB0[ct], d);
      d = MFMA(xc1, wvB1[ct], d);
      union { u32 u[2]; bf16x4 v; } pv;
      pv.u[0] = packbf_t(d[1], d[0]);
      pv.u[1] = packbf_t(d[3], d[2]);
      vf[ct] = pv.v;
    }

    // S^T = x·QW^T + cq: D[key-row][query=mm]; exp -> MFMA16 B-frag
#pragma unroll
    for (int qt = 0; qt < 4; ++qt) {
      f32x4 s = {cq4[qt], cq4[qt], cq4[qt], cq4[qt]};
      s = MFMA(xc0, qwf0[qt], s);
      s = MFMA(xc1, qwf1[qt], s);
      const float e0 = __expf(s[0]), e1 = __expf(s[1]);
      const float e2 = __expf(s[2]), e3 = __expf(s[3]);
      rp[qt] += (e0 + e1) + (e2 + e3);
      union { u32 u[2]; bf16x4 v; } pb;
      pb.u[0] = packbf_t(e1, e0);
      pb.u[1] = packbf_t(e3, e2);
#pragma unroll
      for (int ct = 0; ct < 4; ++ct) z[qt][ct] = MFMA16(vf[ct], pb.v, z[qt][ct]);
    }

    xc0 = xn0;
    xc1 = xn1;
  }

  __syncthreads();  // all waves past their QW/cql reads -> pool reusable

  // ---- publish partials
#pragma unroll
  for (int qt = 0; qt < 4; ++qt) {
    float v = rp[qt];
    v += __shfl_xor(v, 16);
    v += __shfl_xor(v, 32);
    if (q == 0) rsw[w][qt * 16 + mm] = v;
#pragma unroll
    for (int ct = 0; ct < 4; ++ct) {
      uint2 val;
      val.x = packbf_t(z[qt][ct][1], z[qt][ct][0]);
      val.y = packbf_t(z[qt][ct][3], z[qt][ct][2]);
      *(uint2*)(zcb + w * 4352 + (qt * 16 + mm) * 68 + ct * 16 + q * 4) = val;
    }
  }
  __syncthreads();

  // ---- combine 4 key-splits, normalize, store bf16 (B,N,128)
  const int c2 = tid & 31, qr = tid >> 5;
#pragma unroll
  for (int i = 0; i < 8; ++i) {
    const int query = qr + i * 8;
    const float rt = rsw[0][query] + rsw[1][query] + rsw[2][query] + rsw[3][query];
    const float rinv = __builtin_amdgcn_rcpf(rt);
    float vlo = 0.f, vhi = 0.f;
#pragma unroll
    for (int ww = 0; ww < 4; ++ww) {
      const u32 u = *(const u32*)(zcb + ww * 4352 + query * 68 + c2 * 2);
      vlo += __uint_as_float(u << 16);
      vhi += __uint_as_float(u & 0xffff0000u);
    }
    vlo *= rinv;
    vhi *= rinv;
    *(u32*)(Ztb + (b * 1024 + q0 + query) * 128 + br * 64 + c2 * 2) = packbf_t(vhi, vlo);
  }
}

// ---------------------------------------------------------------------------
// Kernel 2: fused zproj (128->128) + final (192->192) + gates, all MFMA.
// Weights converted fp32->bf16 inline; gate-major row index computed inline.
// grid (16 b, 32 nt): linear%8 == b%8 matches fused_attn's Ztb writers.
// ---------------------------------------------------------------------------
__global__ __launch_bounds__(256) void tail_kernel(
    const u16* __restrict__ Ztb, const u16* __restrict__ hbuf,
    const float* __restrict__ m_, const float* __restrict__ Wz,
    const float* __restrict__ bz, const float* __restrict__ Wm,
    const float* __restrict__ bm, float* __restrict__ out)
{
  const int b = blockIdx.x, n0 = blockIdx.y * 32;
  __shared__ __align__(16) u16 zp[32][136];  // bf16 Zp tile [px][c]
  const int tid = threadIdx.x, lane = tid & 63, wv = tid >> 6;
  const int mm = lane & 15, q = lane >> 4;
  const int pxt = wv & 1, oh = wv >> 1;

  // ---- Phase A: Zp = Wz @ [Zh;Zm] + bz  (A=W: lane rows = contiguous o-ch)
  {
    bf16x8 za[4];
#pragma unroll
    for (int ks = 0; ks < 4; ++ks)
      za[ks] = *(const bf16x8*)(Ztb + (b * 1024 + n0 + pxt * 16 + mm) * 128 +
                                ks * 32 + q * 8);
#pragma unroll
    for (int ot = 0; ot < 4; ++ot) {
      const int o0 = oh * 64 + ot * 16;
      const float4 b4 = *(const float4*)(bz + o0 + q * 4);
      f32x4 d = {b4.x, b4.y, b4.z, b4.w};
#pragma unroll
      for (int ks = 0; ks < 4; ++ks) {
        const bf16x8 wb = ld8bf(Wz + (o0 + mm) * 128 + ks * 32 + q * 8);
        d = MFMA(wb, za[ks], d);
      }
      uint2 val;
      val.x = packbf(d[0], d[1]);
      val.y = packbf(d[2], d[3]);
      *(uint2*)&zp[pxt * 16 + mm][o0 + q * 4] = val;
    }
  }
  __syncthreads();

  // ---- Phase B: combined = Wm @ [Zp; h] + bm (gate-major row o inline)
  {
    const int hb2 = oh;
    bf16x8 fa[6];
#pragma unroll
    for (int ks = 0; ks < 4; ++ks)
      fa[ks] = *(const bf16x8*)&zp[pxt * 16 + mm][ks * 32 + q * 8];
    {
      const u16* hp = hbuf + (b * 1024 + n0 + pxt * 16 + mm) * 64;
      fa[4] = *(const bf16x8*)(hp + q * 8);
      fa[5] = *(const bf16x8*)(hp + 32 + q * 8);
    }
    f32x4 dd[6];
#pragma unroll
    for (int j = 0; j < 6; ++j) {
      const int o = (j % 3) * 64 + (hb2 * 2 + j / 3) * 16 + mm;
      const float bb = bm[o];
      f32x4 d = {bb, bb, bb, bb};
#pragma unroll
      for (int ks = 0; ks < 6; ++ks) {
        const bf16x8 wb = ld8bf(Wm + o * 192 + ks * 32 + q * 8);
        d = MFMA(fa[ks], wb, d);
      }
      dd[j] = d;
    }
#pragma unroll
    for (int ctl = 0; ctl < 2; ++ctl) {
      const int c = (hb2 * 2 + ctl) * 16 + mm;
      const int px = n0 + pxt * 16 + q * 4;
      const float4 mold = *(const float4*)(m_ + (b * 64 + c) * 1024 + px);
      float4 nh, nm;
#pragma unroll
      for (int r = 0; r < 4; ++r) {
        const float xo = dd[ctl * 3 + 0][r];
        const float xg = dd[ctl * 3 + 1][r];
        const float xi = dd[ctl * 3 + 2][r];
        const float si = __builtin_amdgcn_rcpf(1.f + __expf(-xi));
        const float th = 1.f - 2.f * __builtin_amdgcn_rcpf(__expf(2.f * xg) + 1.f);
        const float so = __builtin_amdgcn_rcpf(1.f + __expf(-xo));
        const float mo = ((const float*)&mold)[r];
        const float nmv = (1.f - si) * mo + si * th;
        ((float*)&nm)[r] = nmv;
        ((float*)&nh)[r] = so * nmv;
      }
      *(float4*)(out + (b * 64 + c) * 1024 + px) = nh;
      *(float4*)(out + 1048576 + (b * 64 + c) * 1024 + px) = nm;
    }
  }
}

// ---------------------------------------------------------------------------
extern "C" void kernel_launch(void* const* d_in, const int* in_sizes, int n_in,
                              void* d_out, int out_size, void* d_ws, size_t ws_size,
                              hipStream_t stream) {
  const float* h   = (const float*)d_in[0];
  const float* m   = (const float*)d_in[1];
  const float* Wq  = (const float*)d_in[2];
  const float* bq  = (const float*)d_in[3];
  const float* Wk  = (const float*)d_in[4];
  const float* bk  = (const float*)d_in[5];
  const float* Wk2 = (const float*)d_in[6];
  const float* bk2 = (const float*)d_in[7];
  const float* Wv  = (const float*)d_in[8];
  const float* bv  = (const float*)d_in[9];
  const float* Wv2 = (const float*)d_in[10];
  const float* bv2 = (const float*)d_in[11];
  const float* Wz  = (const float*)d_in[12];
  const float* bz  = (const float*)d_in[13];
  const float* Wm  = (const float*)d_in[14];
  const float* bm  = (const float*)d_in[15];
  float* out = (float*)d_out;

  char* ws = (char*)d_ws;
  const size_t MB = 1024 * 1024;
  u16* hbuf = (u16*)(ws + 0 * MB);   // (B,N,64) bf16 h^T
  u16* mbuf = (u16*)(ws + 2 * MB);   // (B,N,64) bf16 m^T
  u16* Ztb  = (u16*)(ws + 4 * MB);   // (B,N,128) bf16

  prep_kernel<<<dim3(16, 16), 256, 0, stream>>>(h, m, hbuf, mbuf);
  fused_attn_kernel<<<512, 256, 0, stream>>>(hbuf, mbuf, Wq, bq, Wk, bk, Wk2, bk2,
                                             Wv, bv, Wv2, bv2, Ztb);
  tail_kernel<<<dim3(16, 32), 256, 0, stream>>>(Ztb, hbuf, m, Wz, bz, Wm, bm, out);
}